// Round 9
// baseline (409.504 us; speedup 1.0000x reference)
//
#include <hip/hip_runtime.h>
#include <stdint.h>
#include <stddef.h>

// ---------- types ----------
typedef __attribute__((ext_vector_type(4)))  int   i32x4;    // MFMA i8 operand / acc
typedef __attribute__((ext_vector_type(8)))  short bf16x8;
typedef __attribute__((ext_vector_type(4)))  float f32x4;
typedef __attribute__((ext_vector_type(4)))  float f32x4v;
typedef __attribute__((ext_vector_type(4)))  unsigned short u16x4;

__device__ __forceinline__ unsigned short f2bf(float f) {
    union { float f; unsigned u; } v; v.f = f;
    unsigned r = v.u + 0x7FFFu + ((v.u >> 16) & 1u);
    return (unsigned short)(r >> 16);
}

__device__ __forceinline__ void gload_lds16(const void* g, void* l) {
    __builtin_amdgcn_global_load_lds(
        (const __attribute__((address_space(1))) void*)(g),
        (__attribute__((address_space(3))) void*)(l), 16, 0, 0);
}

__device__ __forceinline__ int pack4(float a, float b, float c, float d, float inv) {
    int r0 = ((int)rintf(a * inv)) & 255;
    int r1 = ((int)rintf(b * inv)) & 255;
    int r2 = ((int)rintf(c * inv)) & 255;
    int r3 = ((int)rintf(d * inv)) & 255;
    return r0 | (r1 << 8) | (r2 << 16) | (r3 << 24);
}

// ---------- convert: x fp32 -> int8 per-row dynamic quant (+ sx per row) ----------
__global__ void cvt_x_q8(const float* __restrict__ x, signed char* __restrict__ xq,
                         float* __restrict__ sx, int K) {
    const int row = blockIdx.x;
    const int t   = threadIdx.x;          // 256 threads
    const float* xr = x + (size_t)row * K;
    const int ng = K / 1024;              // f32x4 groups per thread (K=4096 -> 4)

    f32x4v v[8];
    float am = 0.f;
#pragma unroll
    for (int i = 0; i < 8; ++i) {
        if (i < ng) {
            v[i] = __builtin_nontemporal_load(&((const f32x4v*)xr)[i * 256 + t]);
            am = fmaxf(am, fmaxf(fmaxf(fabsf(v[i][0]), fabsf(v[i][1])),
                                 fmaxf(fabsf(v[i][2]), fabsf(v[i][3]))));
        }
    }
#pragma unroll
    for (int m = 32; m >= 1; m >>= 1) am = fmaxf(am, __shfl_xor(am, m, 64));
    __shared__ float red[4];
    const int w = t >> 6;
    if ((t & 63) == 0) red[w] = am;
    __syncthreads();
    am = fmaxf(fmaxf(red[0], red[1]), fmaxf(red[2], red[3]));

    const float inv = (am > 0.f) ? 127.0f / am : 0.f;
    if (t == 0) sx[row] = (am > 0.f) ? am / 127.0f : 0.f;

    int* oq = (int*)(xq + (size_t)row * K);
#pragma unroll
    for (int i = 0; i < 8; ++i)
        if (i < ng) oq[i * 256 + t] = pack4(v[i][0], v[i][1], v[i][2], v[i][3], inv);
}

// ---------- convert: W int32 -> int8 (values already int8-ranged; exact) ----------
__global__ void cvt_w_q8(const int* __restrict__ w, signed char* __restrict__ o, int n4) {
    int i = blockIdx.x * blockDim.x + threadIdx.x;
    int stride = gridDim.x * blockDim.x;
    for (; i < n4; i += stride) {
        i32x4 a = __builtin_nontemporal_load(&((const i32x4*)w)[i]);
        ((int*)o)[i] = (a[0] & 255) | ((a[1] & 255) << 8) | ((a[2] & 255) << 16) | ((a[3] & 255) << 24);
    }
}

// =====================================================================
// 256x256 int8 GEMM v9 = v7 + cross-tile A-frag register prefetch.
// v7 finding: per-tile wall 4800cy vs MFMA 2611 + LDS 2688 (sum 5300) ->
// read-burst and MFMA-burst are serialized (8 waves lockstep). Fix:
// prefetch tile t+1's AF frags (8 ds_read_b128 from the OTHER buffer's
// stable A region) during tile t's P4 MFMA cluster; P1 of t+1 then has
// only 4 bF reads on its critical path.
// vmcnt ledger (audited; 4 gloads per A or B tile-stage):
//   tile t entry: A(t+1)4 in flight.
//   P1 stages B0(t+1)2, P2 stages B1(t+1)2, P4 stages A(t+2)4 -> 12.
//   P4: VM8 (drains A(t+1), prefetch-safe), prefetch, MFMA, VM4
//   (drains B(t+1), leaves A(t+2)), boundary BAR.
//   prologue: VM0 once (A0,B0,A1 resident); read AF(tile0).
//   tails: NT-2 {VM4@P4, VM0@boundary}, NT-1 {no stage/prefetch}.
// All other components byte-identical to v7 (proven: 0 conflicts,
// FETCH 295MB supertile remap, WRITE 262MB plain stores).
// =====================================================================
#define BM8 256
#define BN8 256
#define BKQ 128   // int8 elems per K-tile (=128 B rows)

__global__ __launch_bounds__(512, 2) void gemm8p_i8(
    const signed char* __restrict__ A,   // [M][K] i8
    const signed char* __restrict__ Bw,  // [N][K] i8
    const float* __restrict__ sx,        // [M] per-row x scale
    const float* __restrict__ scale_p,
    const float* __restrict__ bias,
    float* __restrict__ C,
    int M, int N, int K)
{
    __shared__ __align__(16) char smem[131072];

    const int t    = threadIdx.x;
    const int lane = t & 63;
    const int w    = t >> 6;
    const int wm   = w >> 2;     // 0..1 (128-row half)
    const int wn   = w & 3;      // 0..3 (64-col quarter)

    const int ntn = N / BN8;
    const int ntm = M / BM8;
    int nwg = gridDim.x, bid = blockIdx.x;
    int tm, tn;
    if (((nwg & 7) == 0) && (ntm % 8 == 0)) {
        const int x = bid & 7, c = bid >> 3;
        const int tmB = ntm >> 3;
        tm = x * tmB + (c % tmB);
        tn = c / tmB;
    } else if ((nwg & 7) == 0) {
        int swz = (bid & 7) * (nwg >> 3) + (bid >> 3);
        tm = swz / ntn; tn = swz % ntn;
    } else {
        tm = bid / ntn; tn = bid % ntn;
    }
    const int row0 = tm * BM8;
    const int col0 = tn * BN8;

    const int Kb = K;                // row stride BYTES (i8)
    const int NT = K / BKQ;

    const int srow = w * 8 + (lane >> 3);
    const int sc2  = ((lane & 7) ^ (lane >> 3)) * 16;
    const int ldsLaneOff = w * 1024 + lane * 16;

    const char* aG = (const char*)A + (size_t)(row0 + srow) * Kb + sc2;
    const char* bG = (const char*)Bw + (size_t)(col0 + srow) * Kb + sc2;

    // 16x16 frag-read geometry (measured conflict-free)
    const int q    = lane >> 4;        // 0..3 k-chunk
    const int lr   = lane & 15;        // row within 16
    const int swzr = (lr & 7) << 4;    // read-side XOR

    i32x4 acc[8][4] = {};
    i32x4 AFa[4][2], AFb[4][2], aS[4][2], bF[2][2], bS[2][2];

#define STG(gbase, h, tj, buf, region) do {                                   \
    const char* _g = (gbase) + (size_t)(h) * 128 * Kb + (size_t)(tj) * 128;   \
    char* _l = &smem[(buf) * 65536 + (region) * 16384 + ldsLaneOff];          \
    gload_lds16(_g, _l);                                                      \
    gload_lds16(_g + (size_t)64 * Kb, _l + 8192);                             \
} while (0)

#define RDA(buf, mi, ks) \
    (*(const i32x4*)&smem[(buf) * 65536 + wm * 16384 + ((mi) * 16 + lr) * 128 \
                          + ((((ks) << 6) | (q << 4)) ^ swzr)])
#define RDB(buf, nj, ks) \
    (*(const i32x4*)&smem[(buf) * 65536 + (2 + (wn >> 1)) * 16384              \
                          + ((wn & 1) * 64 + (nj) * 16 + lr) * 128             \
                          + ((((ks) << 6) | (q << 4)) ^ swzr)])

#define MFMA_(a, b, c) (c) = __builtin_amdgcn_mfma_i32_16x16x64_i8((a), (b), (c), 0, 0, 0)
#define BAR() __builtin_amdgcn_s_barrier()
#define FENCE() asm volatile("" ::: "memory")
#define VM8() asm volatile("s_waitcnt vmcnt(8)" ::: "memory")
#define VM4() asm volatile("s_waitcnt vmcnt(4)" ::: "memory")
#define VM0() asm volatile("s_waitcnt vmcnt(0)" ::: "memory")
#define VMNONE() do { } while (0)

// One K-tile. AFC = this tile's prefetched A[m0-3] frags; AFN = prefetch
// target for next tile (read from buf bb^1's A region, which holds
// A(t+1), drained by PVMW).
#define TILE_STEP(tt, bb, AFC, AFN, PF, stB, stA2, PVMW, VMW) do {                    \
    /* P1: bF reads; stage B0(t+1); MFMA (m0-3 x n0-1) using AFC */                   \
    _Pragma("unroll") for (int nj = 0; nj < 2; ++nj) {                                \
        bF[nj][0] = RDB(bb, nj, 0); bF[nj][1] = RDB(bb, nj, 1); }                     \
    if (stB) STG(bG, 0, (tt) + 1, (bb) ^ 1, 2);                                       \
    __builtin_amdgcn_s_setprio(1);                                                    \
    _Pragma("unroll") for (int mi = 0; mi < 4; ++mi)                                  \
    _Pragma("unroll") for (int nj = 0; nj < 2; ++nj) {                                \
        MFMA_(AFC[mi][0], bF[nj][0], acc[mi][nj]);                                    \
        MFMA_(AFC[mi][1], bF[nj][1], acc[mi][nj]); }                                  \
    __builtin_amdgcn_s_setprio(0);                                                    \
    /* P2: bS reads; stage B1(t+1); MFMA (m0-3 x n2-3); AFC dies */                   \
    _Pragma("unroll") for (int nj = 0; nj < 2; ++nj) {                                \
        bS[nj][0] = RDB(bb, 2 + nj, 0); bS[nj][1] = RDB(bb, 2 + nj, 1); }             \
    if (stB) STG(bG, 1, (tt) + 1, (bb) ^ 1, 3);                                       \
    __builtin_amdgcn_s_setprio(1);                                                    \
    _Pragma("unroll") for (int mi = 0; mi < 4; ++mi)                                  \
    _Pragma("unroll") for (int nj = 0; nj < 2; ++nj) {                                \
        MFMA_(AFC[mi][0], bS[nj][0], acc[mi][2 + nj]);                                \
        MFMA_(AFC[mi][1], bS[nj][1], acc[mi][2 + nj]); }                              \
    __builtin_amdgcn_s_setprio(0);                                                    \
    /* P3: aS reads; MFMA (m4-7 x n2-3); bS dies */                                   \
    _Pragma("unroll") for (int mi = 0; mi < 4; ++mi) {                                \
        aS[mi][0] = RDA(bb, 4 + mi, 0); aS[mi][1] = RDA(bb, 4 + mi, 1); }             \
    __builtin_amdgcn_s_setprio(1);                                                    \
    _Pragma("unroll") for (int mi = 0; mi < 4; ++mi)                                  \
    _Pragma("unroll") for (int nj = 0; nj < 2; ++nj) {                                \
        MFMA_(aS[mi][0], bS[nj][0], acc[4 + mi][2 + nj]);                             \
        MFMA_(aS[mi][1], bS[nj][1], acc[4 + mi][2 + nj]); }                           \
    __builtin_amdgcn_s_setprio(0);                                                    \
    BAR(); FENCE();   /* mid: all reads of bb.A complete chip-wide */                 \
    /* P4: stage A(t+2); PVMW (A(t+1) landed); prefetch AFN from bb^1.A;              \
       bF re-read; MFMA (m4-7 x n0-1); boundary VMW */                                \
    if (stA2) { STG(aG, 0, (tt) + 2, (bb), 0); STG(aG, 1, (tt) + 2, (bb), 1); }       \
    PVMW();                                                                           \
    if (PF) {                                                                         \
        _Pragma("unroll") for (int mi = 0; mi < 4; ++mi) {                            \
            AFN[mi][0] = RDA((bb) ^ 1, mi, 0); AFN[mi][1] = RDA((bb) ^ 1, mi, 1); }   \
    }                                                                                 \
    _Pragma("unroll") for (int nj = 0; nj < 2; ++nj) {                                \
        bF[nj][0] = RDB(bb, nj, 0); bF[nj][1] = RDB(bb, nj, 1); }                     \
    __builtin_amdgcn_s_setprio(1);                                                    \
    _Pragma("unroll") for (int mi = 0; mi < 4; ++mi)                                  \
    _Pragma("unroll") for (int nj = 0; nj < 2; ++nj) {                                \
        MFMA_(aS[mi][0], bF[nj][0], acc[4 + mi][nj]);                                 \
        MFMA_(aS[mi][1], bF[nj][1], acc[4 + mi][nj]); }                               \
    __builtin_amdgcn_s_setprio(0);                                                    \
    VMW();                                                                            \
    BAR(); FENCE();   /* boundary */                                                  \
} while (0)

    // prologue: stage A(0),B(0),A(1); VM0 (all resident); preload AFa(tile0)
    STG(aG, 0, 0, 0, 0); STG(aG, 1, 0, 0, 1);
    STG(bG, 0, 0, 0, 2); STG(bG, 1, 0, 0, 3);
    STG(aG, 0, 1, 1, 0); STG(aG, 1, 1, 1, 1);
    VM0();
    BAR(); FENCE();
#pragma unroll
    for (int mi = 0; mi < 4; ++mi) {
        AFa[mi][0] = RDA(0, mi, 0); AFa[mi][1] = RDA(0, mi, 1);
    }

    for (int tt = 0; tt < NT - 2; tt += 2) {
        TILE_STEP(tt,     0, AFa, AFb, 1, 1, 1, VM8, VM4);
        TILE_STEP(tt + 1, 1, AFb, AFa, 1, 1, 1, VM8, VM4);
    }
    TILE_STEP(NT - 2, 0, AFa, AFb, 1, 1, 0, VM4, VM0);      // no A-stage; drain
    TILE_STEP(NT - 1, 1, AFb, AFa, 0, 0, 0, VMNONE, VMNONE); // pure compute

    // ---- epilogue: y = acc * (sx[row]*s) + bias[col]; plain cached stores ----
    const float s = scale_p[0];
    float bv[4];
#pragma unroll
    for (int nj = 0; nj < 4; ++nj) bv[nj] = bias[col0 + wn * 64 + nj * 16 + lr];
#pragma unroll
    for (int mi = 0; mi < 8; ++mi) {
        const int rbase = row0 + wm * 128 + mi * 16 + q * 4;
        float sxr[4];
#pragma unroll
        for (int j = 0; j < 4; ++j) sxr[j] = sx[rbase + j] * s;
#pragma unroll
        for (int nj = 0; nj < 4; ++nj) {
            const int col = col0 + wn * 64 + nj * 16 + lr;
#pragma unroll
            for (int j = 0; j < 4; ++j)
                C[(size_t)(rbase + j) * N + col] = (float)acc[mi][nj][j] * sxr[j] + bv[nj];
        }
    }
#undef STG
#undef RDA
#undef RDB
#undef TILE_STEP
}

// ---------- fallback: fused fp32->bf16-in-staging GEMM (ws too small / odd shape) ----------
#define BM 128
#define BN 128
#define BK 64

__global__ __launch_bounds__(256, 2) void gemm_fused(
    const float* __restrict__ A,
    const int* __restrict__ Bw,
    const float* __restrict__ scale_p,
    const float* __restrict__ bias,
    float* __restrict__ C,
    int M, int N, int K)
{
    __shared__ unsigned short As[BM * BK];
    __shared__ unsigned short Bs[BN * BK];
    const int t = threadIdx.x, lane = t & 63, w = t >> 6;
    const int wm = w >> 1, wn = w & 1;
    int nwg = gridDim.x, bid = blockIdx.x;
    int swz = (nwg % 8 == 0) ? ((bid & 7) * (nwg >> 3) + (bid >> 3)) : bid;
    const int ntn = N / BN;
    const int row0 = (swz / ntn) * BM, col0 = (swz % ntn) * BN;
    f32x4 acc[4][4] = {};
    const int lr = lane & 15, lkbase = (lane >> 4) * 8;

    for (int kt = 0; kt < K; kt += BK) {
#pragma unroll
        for (int i = 0; i < 8; ++i) {
            const int r = i * 16 + (t >> 4), c = (t & 15) * 4;
            f32x4v v = *(const f32x4v*)&A[(size_t)(row0 + r) * K + kt + c];
            u16x4 o; o[0] = f2bf(v[0]); o[1] = f2bf(v[1]); o[2] = f2bf(v[2]); o[3] = f2bf(v[3]);
            *(u16x4*)&As[r * BK + c] = o;
        }
#pragma unroll
        for (int i = 0; i < 8; ++i) {
            const int r = i * 16 + (t >> 4), c = (t & 15) * 4;
            i32x4 v = *(const i32x4*)&Bw[(size_t)(col0 + r) * K + kt + c];
            u16x4 o; o[0] = f2bf((float)v[0]); o[1] = f2bf((float)v[1]);
                     o[2] = f2bf((float)v[2]); o[3] = f2bf((float)v[3]);
            *(u16x4*)&Bs[r * BK + c] = o;
        }
        __syncthreads();
#pragma unroll
        for (int ks = 0; ks < 2; ++ks) {
            bf16x8 af[4], bfr[4];
#pragma unroll
            for (int m = 0; m < 4; ++m) af[m] = *(const bf16x8*)&As[(wm * 64 + m * 16 + lr) * BK + lkbase + ks * 32];
#pragma unroll
            for (int n = 0; n < 4; ++n) bfr[n] = *(const bf16x8*)&Bs[(wn * 64 + n * 16 + lr) * BK + lkbase + ks * 32];
#pragma unroll
            for (int m = 0; m < 4; ++m)
#pragma unroll
                for (int n = 0; n < 4; ++n)
                    acc[m][n] = __builtin_amdgcn_mfma_f32_16x16x32_bf16(af[m], bfr[n], acc[m][n], 0, 0, 0);
        }
        __syncthreads();
    }
    const float s = scale_p[0];
    const int lq4 = (lane >> 4) * 4;
#pragma unroll
    for (int m = 0; m < 4; ++m)
#pragma unroll
        for (int n = 0; n < 4; ++n) {
            const int col = col0 + wn * 64 + n * 16 + lr;
            const float bv = bias[col];
#pragma unroll
            for (int j = 0; j < 4; ++j) {
                const int row = row0 + wm * 64 + m * 16 + lq4 + j;
                C[(size_t)row * N + col] = acc[m][n][j] * s + bv;
            }
        }
}

extern "C" void kernel_launch(void* const* d_in, const int* in_sizes, int n_in,
                              void* d_out, int out_size, void* d_ws, size_t ws_size,
                              hipStream_t stream) {
    const float* x     = (const float*)d_in[0];
    const int*   w8    = (const int*)d_in[1];
    const float* scale = (const float*)d_in[2];
    const float* bias  = (const float*)d_in[3];
    float* out = (float*)d_out;

    const int N = in_sizes[3];                    // 16384
    const int K = (int)((long)in_sizes[1] / N);   // 4096
    const int M = (int)((long)in_sizes[0] / K);   // 4096

    const size_t needA = (size_t)M * K;           // i8
    const size_t needB = (size_t)N * K;           // i8
    const size_t needS = (size_t)M * sizeof(float);
    const int NT = K / BKQ;

    const bool okShape = (M % BM8 == 0) && (N % BN8 == 0) && (K % BKQ == 0) &&
                         (K % 1024 == 0) && (K / 1024 <= 8) &&
                         (NT >= 4) && ((NT & 1) == 0);

    if (okShape && ws_size >= needA + needB + needS) {
        signed char* Aq = (signed char*)d_ws;
        signed char* Bq = Aq + needA;
        float*       sx = (float*)(Bq + needB);
        cvt_x_q8<<<M, 256, 0, stream>>>(x, Aq, sx, K);
        cvt_w_q8<<<4096, 256, 0, stream>>>(w8, Bq, (int)((size_t)N * K / 4));
        const int nblocks = (M / BM8) * (N / BN8);
        gemm8p_i8<<<nblocks, 512, 0, stream>>>(Aq, Bq, sx, scale, bias, out, M, N, K);
    } else {
        const int nblocks = (M / BM) * (N / BN);
        gemm_fused<<<nblocks, 256, 0, stream>>>(x, w8, scale, bias, out, M, N, K);
    }
}

// Round 10
// 328.512 us; speedup vs baseline: 1.2465x; 1.2465x over previous
//
#include <hip/hip_runtime.h>
#include <stdint.h>
#include <stddef.h>

// ---------- types ----------
typedef __attribute__((ext_vector_type(4)))  int   i32x4;    // MFMA i8 operand / acc
typedef __attribute__((ext_vector_type(8)))  short bf16x8;
typedef __attribute__((ext_vector_type(4)))  float f32x4;
typedef __attribute__((ext_vector_type(4)))  float f32x4v;
typedef __attribute__((ext_vector_type(4)))  unsigned short u16x4;

__device__ __forceinline__ unsigned short f2bf(float f) {
    union { float f; unsigned u; } v; v.f = f;
    unsigned r = v.u + 0x7FFFu + ((v.u >> 16) & 1u);
    return (unsigned short)(r >> 16);
}

__device__ __forceinline__ void gload_lds16(const void* g, void* l) {
    __builtin_amdgcn_global_load_lds(
        (const __attribute__((address_space(1))) void*)(g),
        (__attribute__((address_space(3))) void*)(l), 16, 0, 0);
}

__device__ __forceinline__ int pack4(float a, float b, float c, float d, float inv) {
    int r0 = ((int)rintf(a * inv)) & 255;
    int r1 = ((int)rintf(b * inv)) & 255;
    int r2 = ((int)rintf(c * inv)) & 255;
    int r3 = ((int)rintf(d * inv)) & 255;
    return r0 | (r1 << 8) | (r2 << 16) | (r3 << 24);
}

// ---------- convert: x fp32 -> int8 per-row dynamic quant (+ sx per row) ----------
__global__ void cvt_x_q8(const float* __restrict__ x, signed char* __restrict__ xq,
                         float* __restrict__ sx, int K) {
    const int row = blockIdx.x;
    const int t   = threadIdx.x;          // 256 threads
    const float* xr = x + (size_t)row * K;
    const int ng = K / 1024;              // f32x4 groups per thread (K=4096 -> 4)

    f32x4v v[8];
    float am = 0.f;
#pragma unroll
    for (int i = 0; i < 8; ++i) {
        if (i < ng) {
            v[i] = __builtin_nontemporal_load(&((const f32x4v*)xr)[i * 256 + t]);
            am = fmaxf(am, fmaxf(fmaxf(fabsf(v[i][0]), fabsf(v[i][1])),
                                 fmaxf(fabsf(v[i][2]), fabsf(v[i][3]))));
        }
    }
#pragma unroll
    for (int m = 32; m >= 1; m >>= 1) am = fmaxf(am, __shfl_xor(am, m, 64));
    __shared__ float red[4];
    const int w = t >> 6;
    if ((t & 63) == 0) red[w] = am;
    __syncthreads();
    am = fmaxf(fmaxf(red[0], red[1]), fmaxf(red[2], red[3]));

    const float inv = (am > 0.f) ? 127.0f / am : 0.f;
    if (t == 0) sx[row] = (am > 0.f) ? am / 127.0f : 0.f;

    int* oq = (int*)(xq + (size_t)row * K);
#pragma unroll
    for (int i = 0; i < 8; ++i)
        if (i < ng) oq[i * 256 + t] = pack4(v[i][0], v[i][1], v[i][2], v[i][3], inv);
}

// ---------- convert: W int32 -> int8 (values already int8-ranged; exact) ----------
__global__ void cvt_w_q8(const int* __restrict__ w, signed char* __restrict__ o, int n4) {
    int i = blockIdx.x * blockDim.x + threadIdx.x;
    int stride = gridDim.x * blockDim.x;
    for (; i < n4; i += stride) {
        i32x4 a = __builtin_nontemporal_load(&((const i32x4*)w)[i]);
        ((int*)o)[i] = (a[0] & 255) | ((a[1] & 255) << 8) | ((a[2] & 255) << 16) | ((a[3] & 255) << 24);
    }
}

// =====================================================================
// 256x256 int8 GEMM v10 = v7 with ONE barrier per K-tile.
// Change vs v7: stage BOTH A(t+1) and B(t+1) at tile-t START (1-tile
// lead ~4800cy >> 900cy HBM latency, so the boundary vmcnt(0) is
// pre-drained ~free). Write-after-read safety now comes solely from the
// boundary barrier: all tile t-1 reads of buf^1 completed before any
// wave entered tile t. Mid s_barrier deleted; sched_barrier(0) at the
// tile midpoint is a per-wave scheduling fence only (caps frag live
// ranges at v7's proven <=128-VGPR profile; prevents hoist-spill).
// Unchanged proven components: 128B rows + both-sides XOR swizzle
// (0 conflicts), 16x16x64 i8 MFMA + v5 frag geometry, XCD supertile
// remap (FETCH 295MB), plain cached C stores (WRITE 262MB), setprio
// around MFMA clusters.
// =====================================================================
#define BM8 256
#define BN8 256
#define BKQ 128   // int8 elems per K-tile (=128 B rows)

__global__ __launch_bounds__(512, 2) void gemm8p_i8(
    const signed char* __restrict__ A,   // [M][K] i8
    const signed char* __restrict__ Bw,  // [N][K] i8
    const float* __restrict__ sx,        // [M] per-row x scale
    const float* __restrict__ scale_p,
    const float* __restrict__ bias,
    float* __restrict__ C,
    int M, int N, int K)
{
    __shared__ __align__(16) char smem[131072];

    const int t    = threadIdx.x;
    const int lane = t & 63;
    const int w    = t >> 6;
    const int wm   = w >> 2;     // 0..1 (128-row half)
    const int wn   = w & 3;      // 0..3 (64-col quarter)

    const int ntn = N / BN8;
    const int ntm = M / BM8;
    int nwg = gridDim.x, bid = blockIdx.x;
    int tm, tn;
    if (((nwg & 7) == 0) && (ntm % 8 == 0)) {
        const int x = bid & 7, c = bid >> 3;
        const int tmB = ntm >> 3;
        tm = x * tmB + (c % tmB);
        tn = c / tmB;
    } else if ((nwg & 7) == 0) {
        int swz = (bid & 7) * (nwg >> 3) + (bid >> 3);
        tm = swz / ntn; tn = swz % ntn;
    } else {
        tm = bid / ntn; tn = bid % ntn;
    }
    const int row0 = tm * BM8;
    const int col0 = tn * BN8;

    const int Kb = K;                // row stride BYTES (i8)
    const int NT = K / BKQ;

    const int srow = w * 8 + (lane >> 3);
    const int sc2  = ((lane & 7) ^ (lane >> 3)) * 16;
    const int ldsLaneOff = w * 1024 + lane * 16;

    const char* aG = (const char*)A + (size_t)(row0 + srow) * Kb + sc2;
    const char* bG = (const char*)Bw + (size_t)(col0 + srow) * Kb + sc2;

    // 16x16 frag-read geometry (measured conflict-free)
    const int q    = lane >> 4;        // 0..3 k-chunk
    const int lr   = lane & 15;        // row within 16
    const int swzr = (lr & 7) << 4;    // read-side XOR

    i32x4 acc[8][4] = {};
    i32x4 aF[4][2], aS[4][2], bF[2][2], bS[2][2];

#define STG(gbase, h, tj, buf, region) do {                                   \
    const char* _g = (gbase) + (size_t)(h) * 128 * Kb + (size_t)(tj) * 128;   \
    char* _l = &smem[(buf) * 65536 + (region) * 16384 + ldsLaneOff];          \
    gload_lds16(_g, _l);                                                      \
    gload_lds16(_g + (size_t)64 * Kb, _l + 8192);                             \
} while (0)

#define RDA(buf, mi, ks) \
    (*(const i32x4*)&smem[(buf) * 65536 + wm * 16384 + ((mi) * 16 + lr) * 128 \
                          + ((((ks) << 6) | (q << 4)) ^ swzr)])
#define RDB(buf, nj, ks) \
    (*(const i32x4*)&smem[(buf) * 65536 + (2 + (wn >> 1)) * 16384              \
                          + ((wn & 1) * 64 + (nj) * 16 + lr) * 128             \
                          + ((((ks) << 6) | (q << 4)) ^ swzr)])

#define MFMA_(a, b, c) (c) = __builtin_amdgcn_mfma_i32_16x16x64_i8((a), (b), (c), 0, 0, 0)
#define BAR() __builtin_amdgcn_s_barrier()
#define FENCE() asm volatile("" ::: "memory")
#define VM0() asm volatile("s_waitcnt vmcnt(0)" ::: "memory")

// One K-tile, ONE barrier. stN=1: stage tile t+1 (8 gloads) at start,
// then VM0 (pre-drained: issued a full tile ago) + boundary BAR at end.
// sched_barrier(0) at midpoint caps register live-ranges (no hoisting
// of P3/P4 reads into P1/P2).
#define TILE_STEP(tt, bb, stN) do {                                                   \
    if (stN) {                                                                        \
        STG(aG, 0, (tt) + 1, (bb) ^ 1, 0); STG(aG, 1, (tt) + 1, (bb) ^ 1, 1);         \
        STG(bG, 0, (tt) + 1, (bb) ^ 1, 2); STG(bG, 1, (tt) + 1, (bb) ^ 1, 3);         \
    }                                                                                 \
    /* P1: aF+bF reads; MFMA (m0-3 x n0-1) */                                         \
    _Pragma("unroll") for (int mi = 0; mi < 4; ++mi) {                                \
        aF[mi][0] = RDA(bb, mi, 0); aF[mi][1] = RDA(bb, mi, 1); }                     \
    _Pragma("unroll") for (int nj = 0; nj < 2; ++nj) {                                \
        bF[nj][0] = RDB(bb, nj, 0); bF[nj][1] = RDB(bb, nj, 1); }                     \
    __builtin_amdgcn_s_setprio(1);                                                    \
    _Pragma("unroll") for (int mi = 0; mi < 4; ++mi)                                  \
    _Pragma("unroll") for (int nj = 0; nj < 2; ++nj) {                                \
        MFMA_(aF[mi][0], bF[nj][0], acc[mi][nj]);                                     \
        MFMA_(aF[mi][1], bF[nj][1], acc[mi][nj]); }                                   \
    __builtin_amdgcn_s_setprio(0);                                                    \
    /* P2: bS reads; MFMA (m0-3 x n2-3); aF dies */                                   \
    _Pragma("unroll") for (int nj = 0; nj < 2; ++nj) {                                \
        bS[nj][0] = RDB(bb, 2 + nj, 0); bS[nj][1] = RDB(bb, 2 + nj, 1); }             \
    __builtin_amdgcn_s_setprio(1);                                                    \
    _Pragma("unroll") for (int mi = 0; mi < 4; ++mi)                                  \
    _Pragma("unroll") for (int nj = 0; nj < 2; ++nj) {                                \
        MFMA_(aF[mi][0], bS[nj][0], acc[mi][2 + nj]);                                 \
        MFMA_(aF[mi][1], bS[nj][1], acc[mi][2 + nj]); }                               \
    __builtin_amdgcn_s_setprio(0);                                                    \
    __builtin_amdgcn_sched_barrier(0);  /* live-range cap, no sync cost */            \
    /* P3: aS reads; MFMA (m4-7 x n2-3); bS dies */                                   \
    _Pragma("unroll") for (int mi = 0; mi < 4; ++mi) {                                \
        aS[mi][0] = RDA(bb, 4 + mi, 0); aS[mi][1] = RDA(bb, 4 + mi, 1); }             \
    __builtin_amdgcn_s_setprio(1);                                                    \
    _Pragma("unroll") for (int mi = 0; mi < 4; ++mi)                                  \
    _Pragma("unroll") for (int nj = 0; nj < 2; ++nj) {                                \
        MFMA_(aS[mi][0], bS[nj][0], acc[4 + mi][2 + nj]);                             \
        MFMA_(aS[mi][1], bS[nj][1], acc[4 + mi][2 + nj]); }                           \
    __builtin_amdgcn_s_setprio(0);                                                    \
    /* P4: bF re-read; MFMA (m4-7 x n0-1) */                                          \
    _Pragma("unroll") for (int nj = 0; nj < 2; ++nj) {                                \
        bF[nj][0] = RDB(bb, nj, 0); bF[nj][1] = RDB(bb, nj, 1); }                     \
    __builtin_amdgcn_s_setprio(1);                                                    \
    _Pragma("unroll") for (int mi = 0; mi < 4; ++mi)                                  \
    _Pragma("unroll") for (int nj = 0; nj < 2; ++nj) {                                \
        MFMA_(aS[mi][0], bF[nj][0], acc[4 + mi][nj]);                                 \
        MFMA_(aS[mi][1], bF[nj][1], acc[4 + mi][nj]); }                               \
    __builtin_amdgcn_s_setprio(0);                                                    \
    if (stN) { VM0(); BAR(); FENCE(); }   /* boundary: t+1 staged & visible */        \
} while (0)

    // prologue: stage tile0 {A0,A1,B0,B1}; drain; sync
    STG(aG, 0, 0, 0, 0); STG(aG, 1, 0, 0, 1);
    STG(bG, 0, 0, 0, 2); STG(bG, 1, 0, 0, 3);
    VM0();
    BAR(); FENCE();

    for (int tt = 0; tt < NT - 2; tt += 2) {
        TILE_STEP(tt,     0, 1);
        TILE_STEP(tt + 1, 1, 1);
    }
    TILE_STEP(NT - 2, 0, 1);
    TILE_STEP(NT - 1, 1, 0);   // final tile: no stage, no barrier

    // ---- epilogue: y = acc * (sx[row]*s) + bias[col]; plain cached stores ----
    const float s = scale_p[0];
    float bv[4];
#pragma unroll
    for (int nj = 0; nj < 4; ++nj) bv[nj] = bias[col0 + wn * 64 + nj * 16 + lr];
#pragma unroll
    for (int mi = 0; mi < 8; ++mi) {
        const int rbase = row0 + wm * 128 + mi * 16 + q * 4;
        float sxr[4];
#pragma unroll
        for (int j = 0; j < 4; ++j) sxr[j] = sx[rbase + j] * s;
#pragma unroll
        for (int nj = 0; nj < 4; ++nj) {
            const int col = col0 + wn * 64 + nj * 16 + lr;
#pragma unroll
            for (int j = 0; j < 4; ++j)
                C[(size_t)(rbase + j) * N + col] = (float)acc[mi][nj][j] * sxr[j] + bv[nj];
        }
    }
#undef STG
#undef RDA
#undef RDB
#undef TILE_STEP
}

// ---------- fallback: fused fp32->bf16-in-staging GEMM (ws too small / odd shape) ----------
#define BM 128
#define BN 128
#define BK 64

__global__ __launch_bounds__(256, 2) void gemm_fused(
    const float* __restrict__ A,
    const int* __restrict__ Bw,
    const float* __restrict__ scale_p,
    const float* __restrict__ bias,
    float* __restrict__ C,
    int M, int N, int K)
{
    __shared__ unsigned short As[BM * BK];
    __shared__ unsigned short Bs[BN * BK];
    const int t = threadIdx.x, lane = t & 63, w = t >> 6;
    const int wm = w >> 1, wn = w & 1;
    int nwg = gridDim.x, bid = blockIdx.x;
    int swz = (nwg % 8 == 0) ? ((bid & 7) * (nwg >> 3) + (bid >> 3)) : bid;
    const int ntn = N / BN;
    const int row0 = (swz / ntn) * BM, col0 = (swz % ntn) * BN;
    f32x4 acc[4][4] = {};
    const int lr = lane & 15, lkbase = (lane >> 4) * 8;

    for (int kt = 0; kt < K; kt += BK) {
#pragma unroll
        for (int i = 0; i < 8; ++i) {
            const int r = i * 16 + (t >> 4), c = (t & 15) * 4;
            f32x4v v = *(const f32x4v*)&A[(size_t)(row0 + r) * K + kt + c];
            u16x4 o; o[0] = f2bf(v[0]); o[1] = f2bf(v[1]); o[2] = f2bf(v[2]); o[3] = f2bf(v[3]);
            *(u16x4*)&As[r * BK + c] = o;
        }
#pragma unroll
        for (int i = 0; i < 8; ++i) {
            const int r = i * 16 + (t >> 4), c = (t & 15) * 4;
            i32x4 v = *(const i32x4*)&Bw[(size_t)(col0 + r) * K + kt + c];
            u16x4 o; o[0] = f2bf((float)v[0]); o[1] = f2bf((float)v[1]);
                     o[2] = f2bf((float)v[2]); o[3] = f2bf((float)v[3]);
            *(u16x4*)&Bs[r * BK + c] = o;
        }
        __syncthreads();
#pragma unroll
        for (int ks = 0; ks < 2; ++ks) {
            bf16x8 af[4], bfr[4];
#pragma unroll
            for (int m = 0; m < 4; ++m) af[m] = *(const bf16x8*)&As[(wm * 64 + m * 16 + lr) * BK + lkbase + ks * 32];
#pragma unroll
            for (int n = 0; n < 4; ++n) bfr[n] = *(const bf16x8*)&Bs[(wn * 64 + n * 16 + lr) * BK + lkbase + ks * 32];
#pragma unroll
            for (int m = 0; m < 4; ++m)
#pragma unroll
                for (int n = 0; n < 4; ++n)
                    acc[m][n] = __builtin_amdgcn_mfma_f32_16x16x32_bf16(af[m], bfr[n], acc[m][n], 0, 0, 0);
        }
        __syncthreads();
    }
    const float s = scale_p[0];
    const int lq4 = (lane >> 4) * 4;
#pragma unroll
    for (int m = 0; m < 4; ++m)
#pragma unroll
        for (int n = 0; n < 4; ++n) {
            const int col = col0 + wn * 64 + n * 16 + lr;
            const float bv = bias[col];
#pragma unroll
            for (int j = 0; j < 4; ++j) {
                const int row = row0 + wm * 64 + m * 16 + lq4 + j;
                C[(size_t)row * N + col] = acc[m][n][j] * s + bv;
            }
        }
}

extern "C" void kernel_launch(void* const* d_in, const int* in_sizes, int n_in,
                              void* d_out, int out_size, void* d_ws, size_t ws_size,
                              hipStream_t stream) {
    const float* x     = (const float*)d_in[0];
    const int*   w8    = (const int*)d_in[1];
    const float* scale = (const float*)d_in[2];
    const float* bias  = (const float*)d_in[3];
    float* out = (float*)d_out;

    const int N = in_sizes[3];                    // 16384
    const int K = (int)((long)in_sizes[1] / N);   // 4096
    const int M = (int)((long)in_sizes[0] / K);   // 4096

    const size_t needA = (size_t)M * K;           // i8
    const size_t needB = (size_t)N * K;           // i8
    const size_t needS = (size_t)M * sizeof(float);
    const int NT = K / BKQ;

    const bool okShape = (M % BM8 == 0) && (N % BN8 == 0) && (K % BKQ == 0) &&
                         (K % 1024 == 0) && (K / 1024 <= 8) &&
                         (NT >= 4) && ((NT & 1) == 0);

    if (okShape && ws_size >= needA + needB + needS) {
        signed char* Aq = (signed char*)d_ws;
        signed char* Bq = Aq + needA;
        float*       sx = (float*)(Bq + needB);
        cvt_x_q8<<<M, 256, 0, stream>>>(x, Aq, sx, K);
        cvt_w_q8<<<4096, 256, 0, stream>>>(w8, Bq, (int)((size_t)N * K / 4));
        const int nblocks = (M / BM8) * (N / BN8);
        gemm8p_i8<<<nblocks, 512, 0, stream>>>(Aq, Bq, sx, scale, bias, out, M, N, K);
    } else {
        const int nblocks = (M / BM) * (N / BN);
        gemm_fused<<<nblocks, 256, 0, stream>>>(x, w8, scale, bias, out, M, N, K);
    }
}

// Round 11
// 308.171 us; speedup vs baseline: 1.3288x; 1.0660x over previous
//
#include <hip/hip_runtime.h>
#include <stdint.h>
#include <stddef.h>

// ---------- types ----------
typedef __attribute__((ext_vector_type(4)))  int   i32x4;    // MFMA i8 operand / acc
typedef __attribute__((ext_vector_type(8)))  short bf16x8;
typedef __attribute__((ext_vector_type(4)))  float f32x4;
typedef __attribute__((ext_vector_type(4)))  float f32x4v;
typedef __attribute__((ext_vector_type(4)))  unsigned short u16x4;

__device__ __forceinline__ unsigned short f2bf(float f) {
    union { float f; unsigned u; } v; v.f = f;
    unsigned r = v.u + 0x7FFFu + ((v.u >> 16) & 1u);
    return (unsigned short)(r >> 16);
}

__device__ __forceinline__ void gload_lds16(const void* g, void* l) {
    __builtin_amdgcn_global_load_lds(
        (const __attribute__((address_space(1))) void*)(g),
        (__attribute__((address_space(3))) void*)(l), 16, 0, 0);
}

__device__ __forceinline__ int pack4(float a, float b, float c, float d, float inv) {
    int r0 = ((int)rintf(a * inv)) & 255;
    int r1 = ((int)rintf(b * inv)) & 255;
    int r2 = ((int)rintf(c * inv)) & 255;
    int r3 = ((int)rintf(d * inv)) & 255;
    return r0 | (r1 << 8) | (r2 << 16) | (r3 << 24);
}

// ---------- merged convert: blocks [0,M) = x-row quant; [M, M+WB) = W pack ----------
__global__ void cvt_xw_q8(const float* __restrict__ x, signed char* __restrict__ xq,
                          float* __restrict__ sx, int K, int M,
                          const int* __restrict__ w, signed char* __restrict__ wq, int n4) {
    __shared__ float red[4];
    const int b = blockIdx.x;
    const int t = threadIdx.x;            // 256 threads

    if (b < M) {
        // ---- x fp32 -> int8 per-row dynamic quant (+ sx per row) ----
        const float* xr = x + (size_t)b * K;
        const int ng = K / 1024;          // f32x4 groups per thread (K=4096 -> 4)
        f32x4v v[8];
        float am = 0.f;
#pragma unroll
        for (int i = 0; i < 8; ++i) {
            if (i < ng) {
                v[i] = __builtin_nontemporal_load(&((const f32x4v*)xr)[i * 256 + t]);
                am = fmaxf(am, fmaxf(fmaxf(fabsf(v[i][0]), fabsf(v[i][1])),
                                     fmaxf(fabsf(v[i][2]), fabsf(v[i][3]))));
            }
        }
#pragma unroll
        for (int m = 32; m >= 1; m >>= 1) am = fmaxf(am, __shfl_xor(am, m, 64));
        const int wv = t >> 6;
        if ((t & 63) == 0) red[wv] = am;
        __syncthreads();
        am = fmaxf(fmaxf(red[0], red[1]), fmaxf(red[2], red[3]));

        const float inv = (am > 0.f) ? 127.0f / am : 0.f;
        if (t == 0) sx[b] = (am > 0.f) ? am / 127.0f : 0.f;

        int* oq = (int*)(xq + (size_t)b * K);
#pragma unroll
        for (int i = 0; i < 8; ++i)
            if (i < ng) oq[i * 256 + t] = pack4(v[i][0], v[i][1], v[i][2], v[i][3], inv);
    } else {
        // ---- W int32 -> int8 (values already int8-ranged; exact) ----
        int i = (b - M) * blockDim.x + t;
        const int stride = (gridDim.x - M) * blockDim.x;
        for (; i < n4; i += stride) {
            i32x4 a = __builtin_nontemporal_load(&((const i32x4*)w)[i]);
            ((int*)wq)[i] = (a[0] & 255) | ((a[1] & 255) << 8) |
                            ((a[2] & 255) << 16) | ((a[3] & 255) << 24);
        }
    }
}

// =====================================================================
// 256x256 int8 GEMM v11 = v7 (best measured: 256.7us) + zero-VALU LDS
// read addressing. Identity: the read byte offset
//   (mi*16+lr)*128 + ((ks<<6|q<<4) ^ ((lr&7)<<4))
// = [lr*128 + e_ks] + mi*2048, where e0 = 16*(q^(lr&7)), e1 = e0^64
// (4 and q occupy disjoint bits). So all 28 ds_read_b128/tile become
// one of 8 loop-invariant per-lane base pointers + compile-time imm
// -> kills ~85 VALU/tile/wave of xor/add address math (VALUBusy 25%).
// Everything else byte-identical to v7: 2-barrier tile, counted VM4,
// both-sides XOR swizzle (0 conflicts), 16x16x64 i8 MFMA, XCD
// supertile remap (FETCH 295MB), plain C stores (WRITE 262MB),
// setprio, A(t+2) staged after mid-barrier (race-audited).
// =====================================================================
#define BM8 256
#define BN8 256
#define BKQ 128   // int8 elems per K-tile (=128 B rows)

__global__ __launch_bounds__(512, 2) void gemm8p_i8(
    const signed char* __restrict__ A,   // [M][K] i8
    const signed char* __restrict__ Bw,  // [N][K] i8
    const float* __restrict__ sx,        // [M] per-row x scale
    const float* __restrict__ scale_p,
    const float* __restrict__ bias,
    float* __restrict__ C,
    int M, int N, int K)
{
    __shared__ __align__(16) char smem[131072];

    const int t    = threadIdx.x;
    const int lane = t & 63;
    const int w    = t >> 6;
    const int wm   = w >> 2;     // 0..1 (128-row half)
    const int wn   = w & 3;      // 0..3 (64-col quarter)

    const int ntn = N / BN8;
    const int ntm = M / BM8;
    int nwg = gridDim.x, bid = blockIdx.x;
    int tm, tn;
    if (((nwg & 7) == 0) && (ntm % 8 == 0)) {
        const int x = bid & 7, c = bid >> 3;
        const int tmB = ntm >> 3;
        tm = x * tmB + (c % tmB);
        tn = c / tmB;
    } else if ((nwg & 7) == 0) {
        int swz = (bid & 7) * (nwg >> 3) + (bid >> 3);
        tm = swz / ntn; tn = swz % ntn;
    } else {
        tm = bid / ntn; tn = bid % ntn;
    }
    const int row0 = tm * BM8;
    const int col0 = tn * BN8;

    const int Kb = K;                // row stride BYTES (i8)
    const int NT = K / BKQ;

    const int srow = w * 8 + (lane >> 3);
    const int sc2  = ((lane & 7) ^ (lane >> 3)) * 16;
    const int ldsLaneOff = w * 1024 + lane * 16;

    const char* aG = (const char*)A + (size_t)(row0 + srow) * Kb + sc2;
    const char* bG = (const char*)Bw + (size_t)(col0 + srow) * Kb + sc2;

    // 16x16 frag-read geometry (measured conflict-free)
    const int q  = lane >> 4;          // 0..3 k-chunk
    const int lr = lane & 15;          // row within 16

    // zero-VALU read addressing: 8 loop-invariant per-lane bases
    const int e0 = (q ^ (lr & 7)) << 4;   // = ((0<<6|q<<4) ^ swzr)
    const int e1 = e0 ^ 64;               // = ((1<<6|q<<4) ^ swzr)
    const char* aRd[2][2];
    const char* bRd[2][2];
    {
        const int aOff = wm * 16384 + lr * 128;
        const int bOff = (2 + (wn >> 1)) * 16384 + ((wn & 1) * 64 + lr) * 128;
        aRd[0][0] = &smem[aOff + e0];          aRd[0][1] = &smem[aOff + e1];
        aRd[1][0] = &smem[65536 + aOff + e0];  aRd[1][1] = &smem[65536 + aOff + e1];
        bRd[0][0] = &smem[bOff + e0];          bRd[0][1] = &smem[bOff + e1];
        bRd[1][0] = &smem[65536 + bOff + e0];  bRd[1][1] = &smem[65536 + bOff + e1];
    }

    i32x4 acc[8][4] = {};
    i32x4 aF[4][2], aS[4][2], bF[2][2], bS[2][2];

#define STG(gbase, h, tj, buf, region) do {                                   \
    const char* _g = (gbase) + (size_t)(h) * 128 * Kb + (size_t)(tj) * 128;   \
    char* _l = &smem[(buf) * 65536 + (region) * 16384 + ldsLaneOff];          \
    gload_lds16(_g, _l);                                                      \
    gload_lds16(_g + (size_t)64 * Kb, _l + 8192);                             \
} while (0)

// buf/ks/mi/nj are all compile-time literals after unroll -> base+imm ds_read
#define RDA(buf, mi, ks) (*(const i32x4*)(aRd[buf][ks] + (mi) * 2048))
#define RDB(buf, nj, ks) (*(const i32x4*)(bRd[buf][ks] + (nj) * 2048))

#define MFMA_(a, b, c) (c) = __builtin_amdgcn_mfma_i32_16x16x64_i8((a), (b), (c), 0, 0, 0)
#define BAR() __builtin_amdgcn_s_barrier()
#define FENCE() asm volatile("" ::: "memory")
#define VM4() asm volatile("s_waitcnt vmcnt(4)" ::: "memory")
#define VM0() asm volatile("s_waitcnt vmcnt(0)" ::: "memory")
#define VMNONE() do { } while (0)

// One K-tile: P1..P3 | mid BAR | P4 | VM | boundary BAR (v5/v7 hazard
// audit: B(t+1) regions' last reads are >=1 boundary-BAR old; A(t+2)
// staged only after mid BAR when all reads of bb.A are chip-wide done).
#define TILE_STEP(tt, bb, stB, stA2, VMW) do {                                        \
    /* P1: aF+bF reads; stage B0(t+1); MFMA (m0-3 x n0-1) */                          \
    _Pragma("unroll") for (int mi = 0; mi < 4; ++mi) {                                \
        aF[mi][0] = RDA(bb, mi, 0); aF[mi][1] = RDA(bb, mi, 1); }                     \
    _Pragma("unroll") for (int nj = 0; nj < 2; ++nj) {                                \
        bF[nj][0] = RDB(bb, nj, 0); bF[nj][1] = RDB(bb, nj, 1); }                     \
    if (stB) STG(bG, 0, (tt) + 1, (bb) ^ 1, 2);                                       \
    __builtin_amdgcn_s_setprio(1);                                                    \
    _Pragma("unroll") for (int mi = 0; mi < 4; ++mi)                                  \
    _Pragma("unroll") for (int nj = 0; nj < 2; ++nj) {                                \
        MFMA_(aF[mi][0], bF[nj][0], acc[mi][nj]);                                     \
        MFMA_(aF[mi][1], bF[nj][1], acc[mi][nj]); }                                   \
    __builtin_amdgcn_s_setprio(0);                                                    \
    /* P2: bS reads; stage B1(t+1); MFMA (m0-3 x n2-3) */                             \
    _Pragma("unroll") for (int nj = 0; nj < 2; ++nj) {                                \
        bS[nj][0] = RDB(bb, 2 + nj, 0); bS[nj][1] = RDB(bb, 2 + nj, 1); }             \
    if (stB) STG(bG, 1, (tt) + 1, (bb) ^ 1, 3);                                       \
    __builtin_amdgcn_s_setprio(1);                                                    \
    _Pragma("unroll") for (int mi = 0; mi < 4; ++mi)                                  \
    _Pragma("unroll") for (int nj = 0; nj < 2; ++nj) {                                \
        MFMA_(aF[mi][0], bS[nj][0], acc[mi][2 + nj]);                                 \
        MFMA_(aF[mi][1], bS[nj][1], acc[mi][2 + nj]); }                               \
    __builtin_amdgcn_s_setprio(0);                                                    \
    /* P3: aS reads; MFMA (m4-7 x n2-3) */                                            \
    _Pragma("unroll") for (int mi = 0; mi < 4; ++mi) {                                \
        aS[mi][0] = RDA(bb, 4 + mi, 0); aS[mi][1] = RDA(bb, 4 + mi, 1); }             \
    __builtin_amdgcn_s_setprio(1);                                                    \
    _Pragma("unroll") for (int mi = 0; mi < 4; ++mi)                                  \
    _Pragma("unroll") for (int nj = 0; nj < 2; ++nj) {                                \
        MFMA_(aS[mi][0], bS[nj][0], acc[4 + mi][2 + nj]);                             \
        MFMA_(aS[mi][1], bS[nj][1], acc[4 + mi][2 + nj]); }                           \
    __builtin_amdgcn_s_setprio(0);                                                    \
    BAR(); FENCE();   /* mid: all P1-P3 reads of bb.A complete chip-wide */           \
    /* P4: bF re-read; stage A0,A1(t+2) into bb; MFMA (m4-7 x n0-1) */                \
    _Pragma("unroll") for (int nj = 0; nj < 2; ++nj) {                                \
        bF[nj][0] = RDB(bb, nj, 0); bF[nj][1] = RDB(bb, nj, 1); }                     \
    if (stA2) { STG(aG, 0, (tt) + 2, (bb), 0); STG(aG, 1, (tt) + 2, (bb), 1); }       \
    __builtin_amdgcn_s_setprio(1);                                                    \
    _Pragma("unroll") for (int mi = 0; mi < 4; ++mi)                                  \
    _Pragma("unroll") for (int nj = 0; nj < 2; ++nj) {                                \
        MFMA_(aS[mi][0], bF[nj][0], acc[4 + mi][nj]);                                 \
        MFMA_(aS[mi][1], bF[nj][1], acc[4 + mi][nj]); }                               \
    __builtin_amdgcn_s_setprio(0);                                                    \
    VMW();                                                                            \
    BAR(); FENCE();   /* boundary: tile t+1 staging landed for all waves */           \
} while (0)

    // prologue: tile0 {A0,A1,B0,B1} + tile1 {A0,A1}; vmcnt(4) -> tile0 resident
    STG(aG, 0, 0, 0, 0); STG(aG, 1, 0, 0, 1);
    STG(bG, 0, 0, 0, 2); STG(bG, 1, 0, 0, 3);
    STG(aG, 0, 1, 1, 0); STG(aG, 1, 1, 1, 1);
    VM4();
    BAR(); FENCE();

    for (int tt = 0; tt < NT - 2; tt += 2) {
        TILE_STEP(tt,     0, 1, 1, VM4);
        TILE_STEP(tt + 1, 1, 1, 1, VM4);
    }
    TILE_STEP(NT - 2, 0, 1, 0, VM0);
    TILE_STEP(NT - 1, 1, 0, 0, VMNONE);

    // ---- epilogue: y = acc * (sx[row]*s) + bias[col]; plain cached stores ----
    const float s = scale_p[0];
    float bv[4];
#pragma unroll
    for (int nj = 0; nj < 4; ++nj) bv[nj] = bias[col0 + wn * 64 + nj * 16 + lr];
#pragma unroll
    for (int mi = 0; mi < 8; ++mi) {
        const int rbase = row0 + wm * 128 + mi * 16 + q * 4;
        float sxr[4];
#pragma unroll
        for (int j = 0; j < 4; ++j) sxr[j] = sx[rbase + j] * s;
#pragma unroll
        for (int nj = 0; nj < 4; ++nj) {
            const int col = col0 + wn * 64 + nj * 16 + lr;
#pragma unroll
            for (int j = 0; j < 4; ++j)
                C[(size_t)(rbase + j) * N + col] = (float)acc[mi][nj][j] * sxr[j] + bv[nj];
        }
    }
#undef STG
#undef RDA
#undef RDB
#undef TILE_STEP
}

// ---------- fallback: fused fp32->bf16-in-staging GEMM (ws too small / odd shape) ----------
#define BM 128
#define BN 128
#define BK 64

__global__ __launch_bounds__(256, 2) void gemm_fused(
    const float* __restrict__ A,
    const int* __restrict__ Bw,
    const float* __restrict__ scale_p,
    const float* __restrict__ bias,
    float* __restrict__ C,
    int M, int N, int K)
{
    __shared__ unsigned short As[BM * BK];
    __shared__ unsigned short Bs[BN * BK];
    const int t = threadIdx.x, lane = t & 63, w = t >> 6;
    const int wm = w >> 1, wn = w & 1;
    int nwg = gridDim.x, bid = blockIdx.x;
    int swz = (nwg % 8 == 0) ? ((bid & 7) * (nwg >> 3) + (bid >> 3)) : bid;
    const int ntn = N / BN;
    const int row0 = (swz / ntn) * BM, col0 = (swz % ntn) * BN;
    f32x4 acc[4][4] = {};
    const int lr = lane & 15, lkbase = (lane >> 4) * 8;

    for (int kt = 0; kt < K; kt += BK) {
#pragma unroll
        for (int i = 0; i < 8; ++i) {
            const int r = i * 16 + (t >> 4), c = (t & 15) * 4;
            f32x4v v = *(const f32x4v*)&A[(size_t)(row0 + r) * K + kt + c];
            u16x4 o; o[0] = f2bf(v[0]); o[1] = f2bf(v[1]); o[2] = f2bf(v[2]); o[3] = f2bf(v[3]);
            *(u16x4*)&As[r * BK + c] = o;
        }
#pragma unroll
        for (int i = 0; i < 8; ++i) {
            const int r = i * 16 + (t >> 4), c = (t & 15) * 4;
            i32x4 v = *(const i32x4*)&Bw[(size_t)(col0 + r) * K + kt + c];
            u16x4 o; o[0] = f2bf((float)v[0]); o[1] = f2bf((float)v[1]);
                     o[2] = f2bf((float)v[2]); o[3] = f2bf((float)v[3]);
            *(u16x4*)&Bs[r * BK + c] = o;
        }
        __syncthreads();
#pragma unroll
        for (int ks = 0; ks < 2; ++ks) {
            bf16x8 af[4], bfr[4];
#pragma unroll
            for (int m = 0; m < 4; ++m) af[m] = *(const bf16x8*)&As[(wm * 64 + m * 16 + lr) * BK + lkbase + ks * 32];
#pragma unroll
            for (int n = 0; n < 4; ++n) bfr[n] = *(const bf16x8*)&Bs[(wn * 64 + n * 16 + lr) * BK + lkbase + ks * 32];
#pragma unroll
            for (int m = 0; m < 4; ++m)
#pragma unroll
                for (int n = 0; n < 4; ++n)
                    acc[m][n] = __builtin_amdgcn_mfma_f32_16x16x32_bf16(af[m], bfr[n], acc[m][n], 0, 0, 0);
        }
        __syncthreads();
    }
    const float s = scale_p[0];
    const int lq4 = (lane >> 4) * 4;
#pragma unroll
    for (int m = 0; m < 4; ++m)
#pragma unroll
        for (int n = 0; n < 4; ++n) {
            const int col = col0 + wn * 64 + n * 16 + lr;
            const float bv = bias[col];
#pragma unroll
            for (int j = 0; j < 4; ++j) {
                const int row = row0 + wm * 64 + m * 16 + lq4 + j;
                C[(size_t)row * N + col] = acc[m][n][j] * s + bv;
            }
        }
}

extern "C" void kernel_launch(void* const* d_in, const int* in_sizes, int n_in,
                              void* d_out, int out_size, void* d_ws, size_t ws_size,
                              hipStream_t stream) {
    const float* x     = (const float*)d_in[0];
    const int*   w8    = (const int*)d_in[1];
    const float* scale = (const float*)d_in[2];
    const float* bias  = (const float*)d_in[3];
    float* out = (float*)d_out;

    const int N = in_sizes[3];                    // 16384
    const int K = (int)((long)in_sizes[1] / N);   // 4096
    const int M = (int)((long)in_sizes[0] / K);   // 4096

    const size_t needA = (size_t)M * K;           // i8
    const size_t needB = (size_t)N * K;           // i8
    const size_t needS = (size_t)M * sizeof(float);
    const int NT = K / BKQ;

    const bool okShape = (M % BM8 == 0) && (N % BN8 == 0) && (K % BKQ == 0) &&
                         (K % 1024 == 0) && (K / 1024 <= 8) &&
                         (NT >= 4) && ((NT & 1) == 0);

    if (okShape && ws_size >= needA + needB + needS) {
        signed char* Aq = (signed char*)d_ws;
        signed char* Bq = Aq + needA;
        float*       sx = (float*)(Bq + needB);
        const int n4 = (int)((size_t)N * K / 4);
        cvt_xw_q8<<<M + 4096, 256, 0, stream>>>(x, Aq, sx, K, M, w8, Bq, n4);
        const int nblocks = (M / BM8) * (N / BN8);
        gemm8p_i8<<<nblocks, 512, 0, stream>>>(Aq, Bq, sx, scale, bias, out, M, N, K);
    } else {
        const int nblocks = (M / BM) * (N / BN);
        gemm_fused<<<nblocks, 256, 0, stream>>>(x, w8, scale, bias, out, M, N, K);
    }
}